// Round 1
// baseline (709.494 us; speedup 1.0000x reference)
//
#include <hip/hip_runtime.h>

#define NPTS   131072          // B*H*W = 32*64*64
#define KCODES 1024
#define DDIM   64
#define CHUNK  128             // emb rows per LDS chunk (32 KB)
#define HWSZ   4096            // H*W

// d_out layout (floats): out[8388608] | loss | perplexity | encodings[131072*1024]
#define OUT_ELEMS   8388608
#define LOSS_OFF    8388608
#define PERP_OFF    8388609
#define ENC_OFF     8388610

// d_ws layout (bytes): [0,4096) e2 f32[1024] | [4096,8192) hist i32[1024] | [8192,10240) blockLoss f32[512]

__global__ __launch_bounds__(256) void e2_kernel(const float* __restrict__ emb,
                                                 float* __restrict__ e2) {
    int k = blockIdx.x * 256 + threadIdx.x;
    const float4* r = (const float4*)(emb + (size_t)k * DDIM);
    float s0 = 0.f, s1 = 0.f, s2 = 0.f, s3 = 0.f;
#pragma unroll
    for (int i = 0; i < 16; ++i) {
        float4 v = r[i];
        s0 = fmaf(v.x, v.x, s0);
        s1 = fmaf(v.y, v.y, s1);
        s2 = fmaf(v.z, v.z, s2);
        s3 = fmaf(v.w, v.w, s3);
    }
    e2[k] = (s0 + s1) + (s2 + s3);
}

__global__ __launch_bounds__(256, 2) void vq_main(
    const float* __restrict__ z_e, const float* __restrict__ emb,
    const float* __restrict__ e2g, float* __restrict__ out,
    float* __restrict__ enc, int* __restrict__ hist,
    float* __restrict__ blockLoss)
{
    __shared__ float se[CHUNK][DDIM];
    __shared__ float se2[CHUNK];
    __shared__ int   sidx[256];
    __shared__ float swsum[4];

    const int tid = threadIdx.x;
    const int bid = blockIdx.x;
    const int n   = bid * 256 + tid;
    const int b   = n >> 12;          // n / 4096
    const int hw  = n & (HWSZ - 1);

    // ---- load this point's 64 channels (stride H*W) into registers ----
    float z[DDIM];
    const float* zp = z_e + (size_t)b * (DDIM * HWSZ) + hw;
#pragma unroll
    for (int d = 0; d < DDIM; ++d) z[d] = zp[(size_t)d * HWSZ];

    float q0 = 0.f, q1 = 0.f, q2 = 0.f, q3 = 0.f;
#pragma unroll
    for (int d = 0; d < DDIM; d += 4) {
        q0 = fmaf(z[d + 0], z[d + 0], q0);
        q1 = fmaf(z[d + 1], z[d + 1], q1);
        q2 = fmaf(z[d + 2], z[d + 2], q2);
        q3 = fmaf(z[d + 3], z[d + 3], q3);
    }
    const float zz = (q0 + q1) + (q2 + q3);

    float best  = 3.4e38f;
    int   bestk = 0;

    for (int kc = 0; kc < KCODES; kc += CHUNK) {
        __syncthreads();
        // cooperative chunk load: CHUNK*DDIM floats = 2048 float4, 8 per thread
        {
            const float4* src = (const float4*)(emb + (size_t)kc * DDIM);
            float4* dst = (float4*)&se[0][0];
#pragma unroll
            for (int i = 0; i < 8; ++i) dst[tid + 256 * i] = src[tid + 256 * i];
            if (tid < CHUNK) se2[tid] = e2g[kc + tid];
        }
        __syncthreads();

        for (int kk = 0; kk < CHUNK; ++kk) {
            const float* er = &se[kk][0];
            float p0 = 0.f, p1 = 0.f, p2 = 0.f, p3 = 0.f;
#pragma unroll
            for (int d = 0; d < DDIM; d += 4) {
                float4 e4 = *(const float4*)(er + d);   // uniform addr -> LDS broadcast
                p0 = fmaf(z[d + 0], e4.x, p0);
                p1 = fmaf(z[d + 1], e4.y, p1);
                p2 = fmaf(z[d + 2], e4.z, p2);
                p3 = fmaf(z[d + 3], e4.w, p3);
            }
            float dist = fmaf(-2.f, (p0 + p1) + (p2 + p3), zz + se2[kk]);
            if (dist < best) { best = dist; bestk = kc + kk; }
        }
    }

    // ---- write quantized output (coalesced per channel: lanes = consecutive w) ----
    {
        const float4* qr = (const float4*)(emb + (size_t)bestk * DDIM);
        float* ob = out + (size_t)b * (DDIM * HWSZ) + hw;
#pragma unroll
        for (int c = 0; c < DDIM; c += 4) {
            float4 q = qr[c >> 2];
            ob[(size_t)(c + 0) * HWSZ] = q.x;
            ob[(size_t)(c + 1) * HWSZ] = q.y;
            ob[(size_t)(c + 2) * HWSZ] = q.z;
            ob[(size_t)(c + 3) * HWSZ] = q.w;
        }
    }

    // ---- histogram (int atomics: exact, order-independent) ----
    atomicAdd(&hist[bestk], 1);

    // ---- per-block loss sum (deterministic, no float atomics) ----
    float s = best;
#pragma unroll
    for (int off = 32; off > 0; off >>= 1) s += __shfl_down(s, off);
    const int lane = tid & 63, wid = tid >> 6;
    if (lane == 0) swsum[wid] = s;
    sidx[tid] = bestk;
    __syncthreads();
    if (tid == 0) blockLoss[bid] = (swsum[0] + swsum[1]) + (swsum[2] + swsum[3]);

    // ---- one-hot encodings: 256 rows per block, coalesced float2 stores ----
    // (enc base is only 8B-aligned: d_out offset 8388610 floats)
    float* encBase = enc + (size_t)bid * 256 * KCODES + tid * 4;
    const int j = tid * 4;
    for (int r = 0; r < 256; ++r) {
        const int ik = sidx[r];
        float2 v0, v1;
        v0.x = (ik == j + 0) ? 1.f : 0.f;
        v0.y = (ik == j + 1) ? 1.f : 0.f;
        v1.x = (ik == j + 2) ? 1.f : 0.f;
        v1.y = (ik == j + 3) ? 1.f : 0.f;
        float2* p = (float2*)(encBase + (size_t)r * KCODES);
        p[0] = v0;
        p[1] = v1;
    }
}

__global__ __launch_bounds__(1024) void fin_kernel(const int* __restrict__ hist,
                                                   const float* __restrict__ blockLoss,
                                                   float* __restrict__ dout)
{
    __shared__ float redE[16];
    __shared__ float redL[16];
    const int t = threadIdx.x;

    float p = (float)hist[t] * (1.f / 131072.f);
    float term = p * logf(p + 1e-10f);
    float lv = (t < 512) ? blockLoss[t] : 0.f;
#pragma unroll
    for (int off = 32; off > 0; off >>= 1) {
        term += __shfl_down(term, off);
        lv   += __shfl_down(lv, off);
    }
    const int lane = t & 63, wid = t >> 6;
    if (lane == 0) { redE[wid] = term; redL[wid] = lv; }
    __syncthreads();
    if (t == 0) {
        float te = 0.f, tl = 0.f;
        for (int i = 0; i < 16; ++i) { te += redE[i]; tl += redL[i]; }
        dout[LOSS_OFF] = 0.25f * tl * (1.f / (131072.f * 64.f));
        dout[PERP_OFF] = expf(-te);
    }
}

extern "C" void kernel_launch(void* const* d_in, const int* in_sizes, int n_in,
                              void* d_out, int out_size, void* d_ws, size_t ws_size,
                              hipStream_t stream) {
    const float* z_e = (const float*)d_in[0];
    const float* emb = (const float*)d_in[1];
    float* out = (float*)d_out;
    float* enc = out + ENC_OFF;

    float* e2        = (float*)d_ws;
    int*   hist      = (int*)((char*)d_ws + 4096);
    float* blockLoss = (float*)((char*)d_ws + 8192);

    hipMemsetAsync((char*)d_ws + 4096, 0, 4096, stream);            // zero hist
    e2_kernel<<<4, 256, 0, stream>>>(emb, e2);
    vq_main<<<NPTS / 256, 256, 0, stream>>>(z_e, emb, e2, out, enc, hist, blockLoss);
    fin_kernel<<<1, 1024, 0, stream>>>(hist, blockLoss, out);
}

// Round 2
// 285.642 us; speedup vs baseline: 2.4839x; 2.4839x over previous
//
#include <hip/hip_runtime.h>

typedef __attribute__((ext_vector_type(8)))  __bf16 bf16x8;
typedef __attribute__((ext_vector_type(16))) float  f32x16;

#define NPTS   131072          // B*H*W = 32*64*64
#define KCODES 1024
#define DDIM   64
#define HWSZ   4096

// d_out layout (floats): out[8388608] | loss | perplexity | encodings[131072*1024]
#define LOSS_OFF    8388608
#define PERP_OFF    8388609
#define ENC_OFF     8388610

// d_ws layout (bytes): [0,4096) e2 f32[1024] | [4096,8192) hist i32[1024] | [8192,10240) blockLoss f32[512]

__device__ __forceinline__ unsigned rnhi(float x) {
    // round-to-nearest-even bf16, returned as fp32 bit pattern (low 16 bits zero)
    unsigned u = __float_as_uint(x);
    return (u + 0x7fffu + ((u >> 16) & 1u)) & 0xffff0000u;
}

__device__ __forceinline__ void split3(float x, unsigned short& h1, unsigned short& h2, unsigned short& h3) {
    unsigned a = rnhi(x); float r1 = x - __uint_as_float(a);
    unsigned b = rnhi(r1); float r2 = r1 - __uint_as_float(b);
    unsigned c = rnhi(r2);
    h1 = (unsigned short)(a >> 16);
    h2 = (unsigned short)(b >> 16);
    h3 = (unsigned short)(c >> 16);
}

__global__ __launch_bounds__(256) void e2_kernel(const float* __restrict__ emb,
                                                 float* __restrict__ e2) {
    int k = blockIdx.x * 256 + threadIdx.x;
    const float4* r = (const float4*)(emb + (size_t)k * DDIM);
    float s0 = 0.f, s1 = 0.f, s2 = 0.f, s3 = 0.f;
#pragma unroll
    for (int i = 0; i < 16; ++i) {
        float4 v = r[i];
        s0 = fmaf(v.x, v.x, s0);
        s1 = fmaf(v.y, v.y, s1);
        s2 = fmaf(v.z, v.z, s2);
        s3 = fmaf(v.w, v.w, s3);
    }
    e2[k] = (s0 + s1) + (s2 + s3);
}

__global__ __launch_bounds__(512, 4) void vq_mfma(
    const float* __restrict__ z_e, const float* __restrict__ emb,
    const float* __restrict__ e2g, float* __restrict__ out,
    float* __restrict__ enc, int* __restrict__ hist,
    float* __restrict__ blockLoss)
{
    // E-chunk planes: 3 splits x 8 k-slots x (128 codes x 8 dims) bf16
    __shared__ unsigned short planeA[3 * 8 * 1024];
    __shared__ float se2[KCODES];
    __shared__ int   sidx[256];
    __shared__ float swsum[8];

    const int tid  = threadIdx.x, bid = blockIdx.x;
    const int lane = tid & 63,    wid = tid >> 6;
    const int hi   = lane >> 5,   col = lane & 31;

    for (int i = tid; i < KCODES; i += 512) se2[i] = e2g[i];

    // ---- build B fragments: this wave's 32 points, 3-way bf16 split of z ----
    const int n  = bid * 256 + wid * 32 + col;
    const int b  = n >> 12, hw = n & (HWSZ - 1);
    const float* zp = z_e + (size_t)b * (DDIM * HWSZ) + hw;

    bf16x8 Bv[3][4];
    float zzp = 0.f;
#pragma unroll
    for (int kk = 0; kk < 4; ++kk) {
        union { unsigned u[4]; bf16x8 v; } p1, p2, p3;
#pragma unroll
        for (int m = 0; m < 4; ++m) {
            float x0 = zp[(size_t)(16 * kk + 8 * hi + 2 * m    ) * HWSZ];
            float x1 = zp[(size_t)(16 * kk + 8 * hi + 2 * m + 1) * HWSZ];
            zzp = fmaf(x0, x0, zzp);
            zzp = fmaf(x1, x1, zzp);
            unsigned short a0, b0, c0, a1, b1, c1;
            split3(x0, a0, b0, c0);
            split3(x1, a1, b1, c1);
            p1.u[m] = (unsigned)a0 | ((unsigned)a1 << 16);
            p2.u[m] = (unsigned)b0 | ((unsigned)b1 << 16);
            p3.u[m] = (unsigned)c0 | ((unsigned)c1 << 16);
        }
        Bv[0][kk] = p1.v; Bv[1][kk] = p2.v; Bv[2][kk] = p3.v;
    }

    float best = 3.4e38f;
    int   bestk = 0;

    for (int chunk = 0; chunk < 8; ++chunk) {
        __syncthreads();
        // ---- stage -2*E chunk (128 codes), 3-way split, [slot][code] layout ----
#pragma unroll
        for (int it = 0; it < 2; ++it) {
            const int code = tid & 127;
            const int sl   = (tid >> 7) + 4 * it;
            const float4* ep = (const float4*)(emb + (size_t)(chunk * 128 + code) * DDIM + sl * 8);
            float4 va = ep[0], vb = ep[1];
            float xs[8] = {va.x, va.y, va.z, va.w, vb.x, vb.y, vb.z, vb.w};
            unsigned w1[4], w2[4], w3[4];
#pragma unroll
            for (int m = 0; m < 4; ++m) {
                unsigned short a0, b0, c0, a1, b1, c1;
                split3(-2.f * xs[2 * m    ], a0, b0, c0);
                split3(-2.f * xs[2 * m + 1], a1, b1, c1);
                w1[m] = (unsigned)a0 | ((unsigned)a1 << 16);
                w2[m] = (unsigned)b0 | ((unsigned)b1 << 16);
                w3[m] = (unsigned)c0 | ((unsigned)c1 << 16);
            }
            const int off = sl * 1024 + code * 8;
            *(uint4*)&planeA[0 * 8192 + off] = make_uint4(w1[0], w1[1], w1[2], w1[3]);
            *(uint4*)&planeA[1 * 8192 + off] = make_uint4(w2[0], w2[1], w2[2], w2[3]);
            *(uint4*)&planeA[2 * 8192 + off] = make_uint4(w3[0], w3[1], w3[2], w3[3]);
        }
        __syncthreads();

        for (int t = 0; t < 4; ++t) {
            f32x16 acc0 = {0.f,0.f,0.f,0.f,0.f,0.f,0.f,0.f,0.f,0.f,0.f,0.f,0.f,0.f,0.f,0.f};
            f32x16 acc1 = {0.f,0.f,0.f,0.f,0.f,0.f,0.f,0.f,0.f,0.f,0.f,0.f,0.f,0.f,0.f,0.f};
            const int arow = (32 * t + col) * 8;
#pragma unroll
            for (int kk = 0; kk < 4; ++kk) {
                const int sb = (2 * kk + hi) * 1024 + arow;
                bf16x8 a1 = *(const bf16x8*)&planeA[0 * 8192 + sb];
                bf16x8 a2 = *(const bf16x8*)&planeA[1 * 8192 + sb];
                bf16x8 a3 = *(const bf16x8*)&planeA[2 * 8192 + sb];
                // 8 product terms (drop only (3,3)); two independent acc chains
                acc0 = __builtin_amdgcn_mfma_f32_32x32x16_bf16(a1, Bv[0][kk], acc0, 0, 0, 0);
                acc1 = __builtin_amdgcn_mfma_f32_32x32x16_bf16(a1, Bv[1][kk], acc1, 0, 0, 0);
                acc0 = __builtin_amdgcn_mfma_f32_32x32x16_bf16(a2, Bv[0][kk], acc0, 0, 0, 0);
                acc1 = __builtin_amdgcn_mfma_f32_32x32x16_bf16(a2, Bv[1][kk], acc1, 0, 0, 0);
                acc0 = __builtin_amdgcn_mfma_f32_32x32x16_bf16(a1, Bv[2][kk], acc0, 0, 0, 0);
                acc1 = __builtin_amdgcn_mfma_f32_32x32x16_bf16(a3, Bv[0][kk], acc1, 0, 0, 0);
                acc0 = __builtin_amdgcn_mfma_f32_32x32x16_bf16(a2, Bv[2][kk], acc0, 0, 0, 0);
                acc1 = __builtin_amdgcn_mfma_f32_32x32x16_bf16(a3, Bv[1][kk], acc1, 0, 0, 0);
            }
            const int cbase = chunk * 128 + 32 * t + 4 * hi;
#pragma unroll
            for (int r = 0; r < 16; ++r) {
                const int row  = (r & 3) + 8 * (r >> 2);   // verified C/D map (+4*hi folded into cbase)
                const int code = cbase + row;
                const float sc = (acc0[r] + acc1[r]) + se2[code];
                if (sc < best) { best = sc; bestk = code; }
            }
        }
    }

    // ---- merge lane pairs (col, col+32): other lane covers the other 16 rows ----
    float obest = __shfl_down(best, 32);
    int   oidx  = __shfl_down(bestk, 32);
    float ozz   = __shfl_down(zzp, 32);
    if (obest < best || (obest == best && oidx < bestk)) { best = obest; bestk = oidx; }
    const float zz = zzp + ozz;
    float contrib = (lane < 32) ? (best + zz) : 0.f;
    if (lane < 32) {
        sidx[wid * 32 + col] = bestk;
        atomicAdd(&hist[bestk], 1);
    }
#pragma unroll
    for (int off = 32; off > 0; off >>= 1) contrib += __shfl_down(contrib, off);
    if (lane == 0) swsum[wid] = contrib;
    __syncthreads();
    if (tid == 0) {
        float s = 0.f;
        for (int i = 0; i < 8; ++i) s += swsum[i];
        blockLoss[bid] = s;
    }

    // ---- quantized output: 2 threads/point, coalesced per channel ----
    {
        const int i  = tid & 255, c0 = (tid >> 8) * 32;
        const int k  = sidx[i];
        const int nn = bid * 256 + i, bb = nn >> 12, hh = nn & (HWSZ - 1);
        const float4* er = (const float4*)(emb + (size_t)k * DDIM + c0);
        float* ob = out + (size_t)bb * (DDIM * HWSZ) + hh;
#pragma unroll
        for (int m = 0; m < 8; ++m) {
            float4 q = er[m];
            ob[(size_t)(c0 + 4 * m    ) * HWSZ] = q.x;
            ob[(size_t)(c0 + 4 * m + 1) * HWSZ] = q.y;
            ob[(size_t)(c0 + 4 * m + 2) * HWSZ] = q.z;
            ob[(size_t)(c0 + 4 * m + 3) * HWSZ] = q.w;
        }
    }

    // ---- one-hot encodings: 256 rows x 4KB, fully coalesced float2 stores ----
    {
        float* ep = enc + (size_t)bid * 256 * KCODES + 2 * tid;
        const int j0 = 2 * tid, j1 = 2 * tid + 1;
        for (int r = 0; r < 256; ++r) {
            const int ik = sidx[r];
            float2 v;
            v.x = (ik == j0) ? 1.f : 0.f;
            v.y = (ik == j1) ? 1.f : 0.f;
            *(float2*)(ep + (size_t)r * KCODES) = v;
        }
    }
}

__global__ __launch_bounds__(1024) void fin_kernel(const int* __restrict__ hist,
                                                   const float* __restrict__ blockLoss,
                                                   float* __restrict__ dout)
{
    __shared__ float redE[16];
    __shared__ float redL[16];
    const int t = threadIdx.x;

    float p = (float)hist[t] * (1.f / 131072.f);
    float term = p * logf(p + 1e-10f);
    float lv = (t < 512) ? blockLoss[t] : 0.f;
#pragma unroll
    for (int off = 32; off > 0; off >>= 1) {
        term += __shfl_down(term, off);
        lv   += __shfl_down(lv, off);
    }
    const int lane = t & 63, wid = t >> 6;
    if (lane == 0) { redE[wid] = term; redL[wid] = lv; }
    __syncthreads();
    if (t == 0) {
        float te = 0.f, tl = 0.f;
        for (int i = 0; i < 16; ++i) { te += redE[i]; tl += redL[i]; }
        dout[LOSS_OFF] = 0.25f * tl * (1.f / (131072.f * 64.f));
        dout[PERP_OFF] = expf(-te);
    }
}

extern "C" void kernel_launch(void* const* d_in, const int* in_sizes, int n_in,
                              void* d_out, int out_size, void* d_ws, size_t ws_size,
                              hipStream_t stream) {
    const float* z_e = (const float*)d_in[0];
    const float* emb = (const float*)d_in[1];
    float* out = (float*)d_out;
    float* enc = out + ENC_OFF;

    float* e2        = (float*)d_ws;
    int*   hist      = (int*)((char*)d_ws + 4096);
    float* blockLoss = (float*)((char*)d_ws + 8192);

    hipMemsetAsync((char*)d_ws + 4096, 0, 4096, stream);            // zero hist
    e2_kernel<<<4, 256, 0, stream>>>(emb, e2);
    vq_mfma<<<NPTS / 256, 512, 0, stream>>>(z_e, emb, e2, out, enc, hist, blockLoss);
    fin_kernel<<<1, 1024, 0, stream>>>(hist, blockLoss, out);
}

// Round 3
// 203.066 us; speedup vs baseline: 3.4939x; 1.4066x over previous
//
#include <hip/hip_runtime.h>

typedef __attribute__((ext_vector_type(8)))  __bf16 bf16x8;
typedef __attribute__((ext_vector_type(16))) float  f32x16;

#define NPTS   131072          // B*H*W = 32*64*64
#define KCODES 1024
#define DDIM   64
#define HWSZ   4096

// d_out layout (floats): out[8388608] | loss | perplexity | encodings[131072*1024]
#define LOSS_OFF    8388608
#define PERP_OFF    8388609
#define ENC_OFF     8388610

// d_ws layout (bytes): [0,4096) e2 f32[1024] | [4096,8192) hist i32[1024] | [8192,10240) blockLoss f32[512]

__device__ __forceinline__ unsigned rnhi(float x) {
    // round-to-nearest-even bf16, returned as fp32 bit pattern (low 16 bits zero)
    unsigned u = __float_as_uint(x);
    return (u + 0x7fffu + ((u >> 16) & 1u)) & 0xffff0000u;
}

__device__ __forceinline__ void split3(float x, unsigned short& h1, unsigned short& h2, unsigned short& h3) {
    unsigned a = rnhi(x); float r1 = x - __uint_as_float(a);
    unsigned b = rnhi(r1); float r2 = r1 - __uint_as_float(b);
    unsigned c = rnhi(r2);
    h1 = (unsigned short)(a >> 16);
    h2 = (unsigned short)(b >> 16);
    h3 = (unsigned short)(c >> 16);
}

__global__ __launch_bounds__(256) void e2_kernel(const float* __restrict__ emb,
                                                 float* __restrict__ e2,
                                                 int* __restrict__ hist) {
    int k = blockIdx.x * 256 + threadIdx.x;
    hist[k] = 0;                       // zero histogram (1024 threads exactly)
    const float4* r = (const float4*)(emb + (size_t)k * DDIM);
    float s0 = 0.f, s1 = 0.f, s2 = 0.f, s3 = 0.f;
#pragma unroll
    for (int i = 0; i < 16; ++i) {
        float4 v = r[i];
        s0 = fmaf(v.x, v.x, s0);
        s1 = fmaf(v.y, v.y, s1);
        s2 = fmaf(v.z, v.z, s2);
        s3 = fmaf(v.w, v.w, s3);
    }
    e2[k] = (s0 + s1) + (s2 + s3);
}

__global__ __launch_bounds__(512, 4) void vq_mfma(
    const float* __restrict__ z_e, const float* __restrict__ emb,
    const float* __restrict__ e2g, float* __restrict__ out,
    float* __restrict__ enc, int* __restrict__ hist,
    float* __restrict__ blockLoss)
{
    // E-chunk planes: 3 splits x 8 k-slots x (128 codes x 8 dims) bf16
    __shared__ unsigned short planeA[3 * 8 * 1024];
    __shared__ float se2[KCODES];
    __shared__ int   sidx[256];
    __shared__ float swsum[8];

    const int tid  = threadIdx.x, bid = blockIdx.x;
    const int lane = tid & 63,    wid = tid >> 6;
    const int hi   = lane >> 5,   col = lane & 31;

    for (int i = tid; i < KCODES; i += 512) se2[i] = e2g[i];

    // this block's 1MB encodings slice (base byte addr ≡ 8 mod 16)
    float* encSlice = enc + (size_t)bid * 256 * KCODES;
    float4* encF4   = (float4*)(encSlice + 2);          // 16B-aligned interior

    // ---- build B fragments: this wave's 32 points, 3-way bf16 split of z ----
    const int n  = bid * 256 + wid * 32 + col;
    const int b  = n >> 12, hw = n & (HWSZ - 1);
    const float* zp = z_e + (size_t)b * (DDIM * HWSZ) + hw;

    bf16x8 Bv[3][4];
    float zzp = 0.f;
#pragma unroll
    for (int kk = 0; kk < 4; ++kk) {
        union { unsigned u[4]; bf16x8 v; } p1, p2, p3;
#pragma unroll
        for (int m = 0; m < 4; ++m) {
            float x0 = zp[(size_t)(16 * kk + 8 * hi + 2 * m    ) * HWSZ];
            float x1 = zp[(size_t)(16 * kk + 8 * hi + 2 * m + 1) * HWSZ];
            zzp = fmaf(x0, x0, zzp);
            zzp = fmaf(x1, x1, zzp);
            unsigned short a0, b0, c0, a1, b1, c1;
            split3(x0, a0, b0, c0);
            split3(x1, a1, b1, c1);
            p1.u[m] = (unsigned)a0 | ((unsigned)a1 << 16);
            p2.u[m] = (unsigned)b0 | ((unsigned)b1 << 16);
            p3.u[m] = (unsigned)c0 | ((unsigned)c1 << 16);
        }
        Bv[0][kk] = p1.v; Bv[1][kk] = p2.v; Bv[2][kk] = p3.v;
    }

    float best = 3.4e38f;
    int   bestk = 0;

    for (int chunk = 0; chunk < 8; ++chunk) {
        __syncthreads();
        // ---- stage -2*E chunk (128 codes), 3-way split, [slot][code] layout ----
#pragma unroll
        for (int it = 0; it < 2; ++it) {
            const int code = tid & 127;
            const int sl   = (tid >> 7) + 4 * it;
            const float4* ep = (const float4*)(emb + (size_t)(chunk * 128 + code) * DDIM + sl * 8);
            float4 va = ep[0], vb = ep[1];
            float xs[8] = {va.x, va.y, va.z, va.w, vb.x, vb.y, vb.z, vb.w};
            unsigned w1[4], w2[4], w3[4];
#pragma unroll
            for (int m = 0; m < 4; ++m) {
                unsigned short a0, b0, c0, a1, b1, c1;
                split3(-2.f * xs[2 * m    ], a0, b0, c0);
                split3(-2.f * xs[2 * m + 1], a1, b1, c1);
                w1[m] = (unsigned)a0 | ((unsigned)a1 << 16);
                w2[m] = (unsigned)b0 | ((unsigned)b1 << 16);
                w3[m] = (unsigned)c0 | ((unsigned)c1 << 16);
            }
            const int off = sl * 1024 + code * 8;
            *(uint4*)&planeA[0 * 8192 + off] = make_uint4(w1[0], w1[1], w1[2], w1[3]);
            *(uint4*)&planeA[1 * 8192 + off] = make_uint4(w2[0], w2[1], w2[2], w2[3]);
            *(uint4*)&planeA[2 * 8192 + off] = make_uint4(w3[0], w3[1], w3[2], w3[3]);
        }
        __syncthreads();

        // ---- fire-and-forget: zero 1/8 of this block's encodings slice ----
        // (drains on the vmem pipe underneath the MFMA tile phase below)
        {
            const float4 z4 = make_float4(0.f, 0.f, 0.f, 0.f);
            const int base = chunk * 8192 + tid;
#pragma unroll
            for (int it = 0; it < 16; ++it) {
                const int idx = base + it * 512;
                if (idx < 65535) encF4[idx] = z4;
            }
            if (chunk == 0) {
                if (tid == 0) *(float2*)encSlice = make_float2(0.f, 0.f);
                if (tid == 1) *(float2*)(encSlice + 262142) = make_float2(0.f, 0.f);
            }
        }

        for (int t = 0; t < 4; ++t) {
            f32x16 acc0 = {0.f,0.f,0.f,0.f,0.f,0.f,0.f,0.f,0.f,0.f,0.f,0.f,0.f,0.f,0.f,0.f};
            f32x16 acc1 = {0.f,0.f,0.f,0.f,0.f,0.f,0.f,0.f,0.f,0.f,0.f,0.f,0.f,0.f,0.f,0.f};
            const int arow = (32 * t + col) * 8;
#pragma unroll
            for (int kk = 0; kk < 4; ++kk) {
                const int sb = (2 * kk + hi) * 1024 + arow;
                bf16x8 a1 = *(const bf16x8*)&planeA[0 * 8192 + sb];
                bf16x8 a2 = *(const bf16x8*)&planeA[1 * 8192 + sb];
                bf16x8 a3 = *(const bf16x8*)&planeA[2 * 8192 + sb];
                // 8 product terms (drop only (3,3)); two independent acc chains
                acc0 = __builtin_amdgcn_mfma_f32_32x32x16_bf16(a1, Bv[0][kk], acc0, 0, 0, 0);
                acc1 = __builtin_amdgcn_mfma_f32_32x32x16_bf16(a1, Bv[1][kk], acc1, 0, 0, 0);
                acc0 = __builtin_amdgcn_mfma_f32_32x32x16_bf16(a2, Bv[0][kk], acc0, 0, 0, 0);
                acc1 = __builtin_amdgcn_mfma_f32_32x32x16_bf16(a2, Bv[1][kk], acc1, 0, 0, 0);
                acc0 = __builtin_amdgcn_mfma_f32_32x32x16_bf16(a1, Bv[2][kk], acc0, 0, 0, 0);
                acc1 = __builtin_amdgcn_mfma_f32_32x32x16_bf16(a3, Bv[0][kk], acc1, 0, 0, 0);
                acc0 = __builtin_amdgcn_mfma_f32_32x32x16_bf16(a2, Bv[2][kk], acc0, 0, 0, 0);
                acc1 = __builtin_amdgcn_mfma_f32_32x32x16_bf16(a3, Bv[1][kk], acc1, 0, 0, 0);
            }
            const int cbase = chunk * 128 + 32 * t + 4 * hi;
#pragma unroll
            for (int r = 0; r < 16; ++r) {
                const int row  = (r & 3) + 8 * (r >> 2);   // verified C/D map (+4*hi folded into cbase)
                const int code = cbase + row;
                const float sc = (acc0[r] + acc1[r]) + se2[code];
                if (sc < best) { best = sc; bestk = code; }
            }
        }
    }

    // ---- merge lane pairs (col, col+32): other lane covers the other 16 rows ----
    float obest = __shfl_down(best, 32);
    int   oidx  = __shfl_down(bestk, 32);
    float ozz   = __shfl_down(zzp, 32);
    if (obest < best || (obest == best && oidx < bestk)) { best = obest; bestk = oidx; }
    const float zz = zzp + ozz;
    float contrib = (lane < 32) ? (best + zz) : 0.f;
    if (lane < 32) {
        sidx[wid * 32 + col] = bestk;
        atomicAdd(&hist[bestk], 1);
    }
#pragma unroll
    for (int off = 32; off > 0; off >>= 1) contrib += __shfl_down(contrib, off);
    if (lane == 0) swsum[wid] = contrib;
    __syncthreads();   // also drains all zero-stores (vmcnt 0 before s_barrier)
    if (tid == 0) {
        float s = 0.f;
        for (int i = 0; i < 8; ++i) s += swsum[i];
        blockLoss[bid] = s;
    }

    // ---- scatter the 1.0s (zeros for this slice are complete & visible) ----
    if (lane < 32) {
        const int nn = bid * 256 + wid * 32 + col;
        enc[(size_t)nn * KCODES + bestk] = 1.0f;
    }

    // ---- quantized output: 2 threads/point, coalesced per channel ----
    {
        const int i  = tid & 255, c0 = (tid >> 8) * 32;
        const int k  = sidx[i];
        const int nn = bid * 256 + i, bb = nn >> 12, hh = nn & (HWSZ - 1);
        const float4* er = (const float4*)(emb + (size_t)k * DDIM + c0);
        float* ob = out + (size_t)bb * (DDIM * HWSZ) + hh;
#pragma unroll
        for (int m = 0; m < 8; ++m) {
            float4 q = er[m];
            ob[(size_t)(c0 + 4 * m    ) * HWSZ] = q.x;
            ob[(size_t)(c0 + 4 * m + 1) * HWSZ] = q.y;
            ob[(size_t)(c0 + 4 * m + 2) * HWSZ] = q.z;
            ob[(size_t)(c0 + 4 * m + 3) * HWSZ] = q.w;
        }
    }
}

__global__ __launch_bounds__(1024) void fin_kernel(const int* __restrict__ hist,
                                                   const float* __restrict__ blockLoss,
                                                   float* __restrict__ dout)
{
    __shared__ float redE[16];
    __shared__ float redL[16];
    const int t = threadIdx.x;

    float p = (float)hist[t] * (1.f / 131072.f);
    float term = p * logf(p + 1e-10f);
    float lv = (t < 512) ? blockLoss[t] : 0.f;
#pragma unroll
    for (int off = 32; off > 0; off >>= 1) {
        term += __shfl_down(term, off);
        lv   += __shfl_down(lv, off);
    }
    const int lane = t & 63, wid = t >> 6;
    if (lane == 0) { redE[wid] = term; redL[wid] = lv; }
    __syncthreads();
    if (t == 0) {
        float te = 0.f, tl = 0.f;
        for (int i = 0; i < 16; ++i) { te += redE[i]; tl += redL[i]; }
        dout[LOSS_OFF] = 0.25f * tl * (1.f / (131072.f * 64.f));
        dout[PERP_OFF] = expf(-te);
    }
}

extern "C" void kernel_launch(void* const* d_in, const int* in_sizes, int n_in,
                              void* d_out, int out_size, void* d_ws, size_t ws_size,
                              hipStream_t stream) {
    const float* z_e = (const float*)d_in[0];
    const float* emb = (const float*)d_in[1];
    float* out = (float*)d_out;
    float* enc = out + ENC_OFF;

    float* e2        = (float*)d_ws;
    int*   hist      = (int*)((char*)d_ws + 4096);
    float* blockLoss = (float*)((char*)d_ws + 8192);

    e2_kernel<<<4, 256, 0, stream>>>(emb, e2, hist);
    vq_mfma<<<NPTS / 256, 512, 0, stream>>>(z_e, emb, e2, out, enc, hist, blockLoss);
    fin_kernel<<<1, 1024, 0, stream>>>(hist, blockLoss, out);
}